// Round 13
// baseline (395.946 us; speedup 1.0000x reference)
//
#include <hip/hip_runtime.h>
#include <math.h>

static constexpr int B_ = 8;
static constexpr int L_ = 4096;
static constexpr int D_ = 512;
static constexpr int U_ = 45;
static constexpr float SCALE_ = 0.04419417382415922f; // 1/sqrt(512)

// ---- workspace layout (offsets in floats) ----
static constexpr size_t OFF_WVMEAN = 0;                      // 512
static constexpr size_t OFF_BV     = 512;                    // 64
static constexpr size_t OFF_WQT    = 576;                    // 512*512
static constexpr size_t OFF_WKT    = OFF_WQT + 262144;       // 512*512
static constexpr size_t OFF_KBAR   = OFF_WKT + 262144;       // (unused, kept)
static constexpr size_t OFF_KW     = OFF_KBAR + 184320;      // 8*45*512
static constexpr size_t OFF_CVEC   = OFF_KW + 184320;        // 384
static constexpr size_t OFF_MEAS   = OFF_CVEC + 384;         // 8*4096
static constexpr size_t OFF_TOPI   = OFF_MEAS + 32768;       // 384 (ints)
static constexpr size_t OFF_QBAR   = OFF_TOPI + 384;         // (unused, kept)
static constexpr size_t OFF_QW     = OFF_QBAR + 184320;      // 8*45*512
static constexpr size_t OFF_DVEC   = OFF_QW + 184320;        // 384
static constexpr size_t OFF_SC     = OFF_DVEC + 384;         // 8*45*4096 (raw scores)
static constexpr size_t OFF_PART   = OFF_SC + 1474560;       // 8 slabs * 8*45*512
static constexpr size_t OFF_SMMX   = OFF_PART + 1474560;     // 360 row maxes
static constexpr size_t OFF_SMIV   = OFF_SMMX + 512;         // 360 row 1/sums
static constexpr size_t OFF_S1     = OFF_SMIV + 512;         // 8*45*512

__device__ __forceinline__ float wave_sum(float v) {
  #pragma unroll
  for (int m = 32; m; m >>= 1) v += __shfl_xor(v, m, 64);
  return v;
}
__device__ __forceinline__ float wave_max(float v) {
  #pragma unroll
  for (int m = 32; m; m >>= 1) v = fmaxf(v, __shfl_xor(v, m, 64));
  return v;
}

// ---- prep: transpose WQ,WK (z<2) + wvmean/bvmean (z==2, first 8 x-blocks) ----
__global__ __launch_bounds__(256) void prep_k(const float* __restrict__ WQ,
    const float* __restrict__ WK, float* __restrict__ wqt, float* __restrict__ wkt,
    const float* __restrict__ WV, const float* __restrict__ bV,
    float* __restrict__ wvmean, float* __restrict__ bvout) {
  const int z = blockIdx.z;
  const int t = threadIdx.x + threadIdx.y * 32;
  if (z < 2) {
    const float* src = z ? WK : WQ;
    float* dst = z ? wkt : wqt;
    __shared__ float tile[32][33];
    int tx = threadIdx.x, ty = threadIdx.y;
    int x = blockIdx.x * 32 + tx;
    int y0 = blockIdx.y * 32;
    for (int r = ty; r < 32; r += 8) tile[r][tx] = src[(size_t)(y0 + r) * 512 + x];
    __syncthreads();
    int xo = y0 + tx;
    int yo0 = blockIdx.x * 32;
    for (int r = ty; r < 32; r += 8) dst[(size_t)(yo0 + r) * 512 + xo] = tile[tx][r];
    return;
  }
  if (blockIdx.y != 0 || blockIdx.x >= 8) return;
  int w = t >> 6, lane = t & 63;
  const float4* W4 = (const float4*)WV;
  int mbase = (blockIdx.x * 4 + w) * 16;
  for (int i = 0; i < 16; ++i) {
    int m = mbase + i;
    float4 a = W4[(size_t)m * 128 + lane];
    float4 c = W4[(size_t)m * 128 + 64 + lane];
    float s = ((a.x + a.y) + (a.z + a.w)) + ((c.x + c.y) + (c.z + c.w));
    s = wave_sum(s);
    if (lane == 0) wvmean[m] = s * (1.0f / 512.0f);
  }
  if (blockIdx.x == 0 && w == 0) {
    const float4* b4 = (const float4*)bV;
    float4 a = b4[lane], c = b4[64 + lane];
    float s = ((a.x + a.y) + (a.z + a.w)) + ((c.x + c.y) + (c.z + c.w));
    s = wave_sum(s);
    if (lane == 0) bvout[0] = s * (1.0f / 512.0f);
  }
}

// ==== fused projection pair: one block per (b, j) row ====
__global__ __launch_bounds__(512) void projpair_k(const float* __restrict__ src,
    const int* __restrict__ idx, const float* __restrict__ W1, const float* __restrict__ b1,
    const float* __restrict__ avec, float* __restrict__ aux,
    const float* __restrict__ W2T, float* __restrict__ outp) {
  const int blk = blockIdx.x;           // 0..359
  const int b = blk / U_, j = blk % U_;
  const int t = threadIdx.x;
  __shared__ float rowA[512];
  __shared__ float rowB[512];
  __shared__ float red[8];

  const float* srow = idx ? (src + ((size_t)b * L_ + idx[b * U_ + j]) * 512)
                          : (src + ((size_t)(b * U_ + j)) * 512);
  rowA[t] = srow[t];
  __syncthreads();

  float a = b1[t];
  #pragma unroll 8
  for (int m = 0; m < 512; ++m) a = fmaf(rowA[m], W1[(size_t)m * 512 + t], a);

  if (aux) {
    float v = wave_sum(a * avec[t]);
    if ((t & 63) == 0) red[t >> 6] = v;
  }
  rowB[t] = a;
  __syncthreads();
  if (aux && t == 0) {
    float s2 = 0.f;
    #pragma unroll
    for (int k = 0; k < 8; ++k) s2 += red[k];
    aux[b * U_ + j] = s2;
  }

  float o = 0.f;
  #pragma unroll 8
  for (int m = 0; m < 512; ++m) o = fmaf(rowB[m], W2T[(size_t)m * 512 + t], o);
  outp[((size_t)(b * U_ + j)) * 512 + t] = o;
}

// ==== s1 = (sum_ls part[ls]) @ WV + bV, one block per (b,j) ====
__global__ __launch_bounds__(512) void s1red_k(const float* __restrict__ part,
    const float* __restrict__ WV, const float* __restrict__ bV, float* __restrict__ s1) {
  const int blk = blockIdx.x;
  const int t = threadIdx.x;
  __shared__ float rowA[512];
  const size_t base = (size_t)blk * 512 + t;
  float s = 0.f;
  #pragma unroll
  for (int ls = 0; ls < 8; ++ls) s += part[(size_t)ls * 184320 + base];
  rowA[t] = s;
  __syncthreads();
  float o = bV[t];
  #pragma unroll 8
  for (int m = 0; m < 512; ++m) o = fmaf(rowA[m], WV[(size_t)m * 512 + t], o);
  s1[(size_t)blk * 512 + t] = o;
}

// ==== meas2p/scores2p: meas2 geometry + attnv5 counted-wait pipeline ====
// block 256 = 16 tx (3 j) x 16 ty (4 l); l-tile 64; 8 supers of 64 k-floats.
// LDS: Qs[2][64][68] + Ks[2][48][68] = 59.5 KB -> 2 blocks/CU, 8 waves/CU.
// Same conflict-free read pattern as meas2 (verified 0-conflict); one raw
// s_barrier per super, vmcnt(0) only at commit (load issued a super earlier).

#define M2P_DECLS                                                              \
  const int t = threadIdx.x;                                                   \
  const int tx = t & 15, ty = t >> 4;                                          \
  const int rswz = (ty >> 1) & 3;                                              \
  __shared__ float Qs[2][64][68];                                              \
  __shared__ float Ks[2][48][68];                                              \
  int lr[4], lc[4], kr[3], kc[3], krr[3];                                      \
  _Pragma("unroll") for (int p = 0; p < 4; ++p) {                              \
    int idx = p * 256 + t; lr[p] = idx >> 4; lc[p] = idx & 15; }               \
  _Pragma("unroll") for (int p = 0; p < 3; ++p) {                              \
    int idx = p * 256 + t; kr[p] = idx >> 4; kc[p] = idx & 15;                 \
    krr[p] = kr[p] < U_ ? kr[p] : U_ - 1; }                                    \
  float4 pq[4], pk[3];                                                         \
  float acc[4][3];                                                             \
  _Pragma("unroll") for (int i = 0; i < 4; ++i) {                              \
    acc[i][0] = 0.f; acc[i][1] = 0.f; acc[i][2] = 0.f; }

#define M2P_ISSUE(S) do { const int k0_ = (S) * 16;                            \
    _Pragma("unroll") for (int p = 0; p < 4; ++p)                              \
      pq[p] = X4[(size_t)lr[p] * 128 + k0_ + lc[p]];                           \
    _Pragma("unroll") for (int p = 0; p < 3; ++p)                              \
      pk[p] = W4[(size_t)krr[p] * 128 + k0_ + kc[p]];                          \
  } while (0)

#define M2P_COMMIT(B) do {                                                     \
    _Pragma("unroll") for (int p = 0; p < 4; ++p) {                            \
      int sw = (lr[p] >> 3) & 3;                                               \
      *(float4*)&Qs[B][lr[p]][(lc[p] ^ sw) * 4] = pq[p];                       \
    }                                                                          \
    _Pragma("unroll") for (int p = 0; p < 3; ++p)                              \
      *(float4*)&Ks[B][kr[p]][kc[p] * 4] = pk[p];                              \
  } while (0)

#define M2P_PIPELINE                                                           \
  M2P_ISSUE(0);                                                                \
  asm volatile("s_waitcnt vmcnt(0)" ::: "memory");                             \
  M2P_COMMIT(0);                                                               \
  M2P_ISSUE(1);                                                                \
  asm volatile("s_waitcnt lgkmcnt(0)" ::: "memory");                           \
  __builtin_amdgcn_s_barrier();                                                \
  __builtin_amdgcn_sched_barrier(0);                                           \
  _Pragma("unroll 1")                                                          \
  for (int s = 0; s < 8; ++s) {                                                \
    const int rb = s & 1;                                                      \
    _Pragma("unroll 4")                                                        \
    for (int kk4 = 0; kk4 < 16; ++kk4) {                                       \
      float4 kv0 = *(const float4*)&Ks[rb][tx * 3 + 0][kk4 * 4];               \
      float4 kv1 = *(const float4*)&Ks[rb][tx * 3 + 1][kk4 * 4];               \
      float4 kv2 = *(const float4*)&Ks[rb][tx * 3 + 2][kk4 * 4];               \
      int qc = (kk4 ^ rswz) * 4;                                               \
      _Pragma("unroll") for (int i = 0; i < 4; ++i) {                          \
        float4 qv = *(const float4*)&Qs[rb][ty * 4 + i][qc];                   \
        acc[i][0] = fmaf(qv.x, kv0.x, acc[i][0]); acc[i][0] = fmaf(qv.y, kv0.y, acc[i][0]); \
        acc[i][0] = fmaf(qv.z, kv0.z, acc[i][0]); acc[i][0] = fmaf(qv.w, kv0.w, acc[i][0]); \
        acc[i][1] = fmaf(qv.x, kv1.x, acc[i][1]); acc[i][1] = fmaf(qv.y, kv1.y, acc[i][1]); \
        acc[i][1] = fmaf(qv.z, kv1.z, acc[i][1]); acc[i][1] = fmaf(qv.w, kv1.w, acc[i][1]); \
        acc[i][2] = fmaf(qv.x, kv2.x, acc[i][2]); acc[i][2] = fmaf(qv.y, kv2.y, acc[i][2]); \
        acc[i][2] = fmaf(qv.z, kv2.z, acc[i][2]); acc[i][2] = fmaf(qv.w, kv2.w, acc[i][2]); \
      }                                                                        \
    }                                                                          \
    if (s + 1 < 8) {                                                           \
      asm volatile("s_waitcnt vmcnt(0)" ::: "memory");                         \
      M2P_COMMIT((s + 1) & 1);                                                 \
      if (s + 2 < 8) M2P_ISSUE(s + 2);                                         \
      asm volatile("s_waitcnt lgkmcnt(0)" ::: "memory");                       \
      __builtin_amdgcn_s_barrier();                                            \
      __builtin_amdgcn_sched_barrier(0);                                       \
    }                                                                          \
  }

__global__ __launch_bounds__(256) void meas2p_k(const float* __restrict__ Q,
    const float* __restrict__ kw, const float* __restrict__ cvec, float* __restrict__ meas) {
  const int b = blockIdx.y;
  const int l0 = blockIdx.x * 64;
  const float4* X4 = (const float4*)(Q + ((size_t)b * L_ + l0) * 512);
  const float4* W4 = (const float4*)(kw + (size_t)b * U_ * 512);
  M2P_DECLS
  M2P_PIPELINE

  const bool valid = (tx < 15);
  float c0 = 0.f, c1 = 0.f, c2 = 0.f;
  if (valid) {
    c0 = cvec[b * U_ + tx * 3 + 0];
    c1 = cvec[b * U_ + tx * 3 + 1];
    c2 = cvec[b * U_ + tx * 3 + 2];
  }
  #pragma unroll
  for (int i = 0; i < 4; ++i) {
    float s0 = acc[i][0] + c0, s1 = acc[i][1] + c1, s2 = acc[i][2] + c2;
    float jmax = valid ? fmaxf(fmaxf(s0, s1), s2) : -3.4e38f;
    float jsum = valid ? (s0 + s1 + s2) : 0.f;
    #pragma unroll
    for (int m = 8; m; m >>= 1) {
      jmax = fmaxf(jmax, __shfl_xor(jmax, m, 64));
      jsum += __shfl_xor(jsum, m, 64);
    }
    if (tx == 0) meas[(size_t)b * L_ + l0 + ty * 4 + i] = jmax - jsum * (1.0f / 45.0f);
  }
}

__global__ __launch_bounds__(256) void scores2p_k(const float* __restrict__ K,
    const float* __restrict__ qw, const float* __restrict__ dvec, float* __restrict__ sc) {
  const int b = blockIdx.y;
  const int l0 = blockIdx.x * 64;
  const float4* X4 = (const float4*)(K + ((size_t)b * L_ + l0) * 512);
  const float4* W4 = (const float4*)(qw + (size_t)b * U_ * 512);
  M2P_DECLS
  M2P_PIPELINE

  if (tx < 15) {
    float d0 = dvec[b * U_ + tx * 3 + 0];
    float d1 = dvec[b * U_ + tx * 3 + 1];
    float d2 = dvec[b * U_ + tx * 3 + 2];
    #pragma unroll
    for (int i = 0; i < 4; ++i) {
      int l = l0 + ty * 4 + i;
      sc[((size_t)(b * U_ + tx * 3 + 0)) * 4096 + l] = (acc[i][0] + d0) * SCALE_;
      sc[((size_t)(b * U_ + tx * 3 + 1)) * 4096 + l] = (acc[i][1] + d1) * SCALE_;
      sc[((size_t)(b * U_ + tx * 3 + 2)) * 4096 + l] = (acc[i][2] + d2) * SCALE_;
    }
  }
}

#undef M2P_DECLS
#undef M2P_ISSUE
#undef M2P_COMMIT
#undef M2P_PIPELINE

// ---- top-45 indices per batch (iterative argmax; ties -> lower index) ----
__global__ __launch_bounds__(256) void topk_k(const float* __restrict__ meas, int* __restrict__ topI) {
  int b = blockIdx.x, t = threadIdx.x;
  __shared__ unsigned long long keys[4096];
  __shared__ unsigned long long wred[4];
  for (int i = t; i < 4096; i += 256) {
    float m = meas[(size_t)b * 4096 + i];
    unsigned u = __float_as_uint(m);
    u = (u & 0x80000000u) ? ~u : (u | 0x80000000u);
    keys[i] = ((unsigned long long)u << 32) | (unsigned)(4095 - i);
  }
  __syncthreads();
  for (int it = 0; it < U_; ++it) {
    unsigned long long lm = 0ull;
    for (int i = t; i < 4096; i += 256) { unsigned long long k = keys[i]; lm = k > lm ? k : lm; }
    #pragma unroll
    for (int m = 32; m; m >>= 1) { unsigned long long o = __shfl_xor(lm, m, 64); lm = o > lm ? o : lm; }
    if ((t & 63) == 0) wred[t >> 6] = lm;
    __syncthreads();
    if (t == 0) {
      unsigned long long f = wred[0];
      for (int k2 = 1; k2 < 4; ++k2) f = wred[k2] > f ? wred[k2] : f;
      int idxl = 4095 - (int)(f & 0xFFFFFFFFull);
      topI[b * U_ + it] = idxl;
      keys[idxl] = 0ull;
    }
    __syncthreads();
  }
}

// ---- softmax reduce only: mx[row], inv[row] = 1/sum(exp(x-mx)) ----
__global__ __launch_bounds__(256) void smred_k(const float* __restrict__ sc,
    float* __restrict__ mxb, float* __restrict__ ivb) {
  int row = blockIdx.x;
  int t = threadIdx.x;
  const float4* s4 = (const float4*)(sc + (size_t)row * 4096);
  __shared__ float red[4];
  float4 v[4];
  #pragma unroll
  for (int p = 0; p < 4; ++p) v[p] = s4[t + p * 256];
  float lmax = -3.4e38f;
  #pragma unroll
  for (int p = 0; p < 4; ++p)
    lmax = fmaxf(lmax, fmaxf(fmaxf(v[p].x, v[p].y), fmaxf(v[p].z, v[p].w)));
  lmax = wave_max(lmax);
  if ((t & 63) == 0) red[t >> 6] = lmax;
  __syncthreads();
  float mx = fmaxf(fmaxf(red[0], red[1]), fmaxf(red[2], red[3]));
  __syncthreads();
  float lsum = 0.f;
  #pragma unroll
  for (int p = 0; p < 4; ++p)
    lsum += expf(v[p].x - mx) + expf(v[p].y - mx) + expf(v[p].z - mx) + expf(v[p].w - mx);
  lsum = wave_sum(lsum);
  if ((t & 63) == 0) red[t >> 6] = lsum;
  __syncthreads();
  if (t == 0) {
    mxb[row] = mx;
    ivb[row] = 1.0f / (red[0] + red[1] + red[2] + red[3]);
  }
}

__device__ __forceinline__ float4 sm4(float4 v, float m, float iv) {
  return make_float4(expf(v.x - m) * iv, expf(v.y - m) * iv,
                     expf(v.z - m) * iv, expf(v.w - m) * iv);
}

// ==== attnV v5 + inline softmax ====
__global__ __launch_bounds__(256) void attnv5_k(const float* __restrict__ V,
    const float* __restrict__ attn, const float* __restrict__ mxb,
    const float* __restrict__ ivb, float* __restrict__ part) {
  const int b = blockIdx.x, ks = blockIdx.y, dh = blockIdx.z;
  const int d0 = dh * 64;
  const int t = threadIdx.x;
  const int tx = t & 15, ty = t >> 4;

  __shared__ float As[2][48][68];
  __shared__ float Vs[2][64][68];

  const float* attnb = attn + (size_t)b * U_ * 4096 + (size_t)ks * 512;
  const float* Vb = V + ((size_t)b * L_ + (size_t)ks * 512) * 512 + d0;

  const int vrow = t >> 4, vc4 = t & 15;
  int arow[3], ac4[3], arr[3];
  float mxv[3], ivv[3];
  #pragma unroll
  for (int p = 0; p < 3; ++p) {
    int idx = p * 256 + t;
    arow[p] = idx >> 4; ac4[p] = idx & 15;
    arr[p] = arow[p] < U_ ? arow[p] : U_ - 1;
    mxv[p] = mxb[b * U_ + arr[p]];
    ivv[p] = ivb[b * U_ + arr[p]];
  }

  float4 pv0, pv1, pv2, pv3, pa0, pa1, pa2;

#define ISSUE(S) do { const int lb_ = (S) * 64;                                  \
    pv0 = *(const float4*)&Vb[(size_t)(lb_ + vrow +  0) * 512 + vc4 * 4];        \
    pv1 = *(const float4*)&Vb[(size_t)(lb_ + vrow + 16) * 512 + vc4 * 4];        \
    pv2 = *(const float4*)&Vb[(size_t)(lb_ + vrow + 32) * 512 + vc4 * 4];        \
    pv3 = *(const float4*)&Vb[(size_t)(lb_ + vrow + 48) * 512 + vc4 * 4];        \
    pa0 = *(const float4*)&attnb[(size_t)arr[0] * 4096 + lb_ + ac4[0] * 4];      \
    pa1 = *(const float4*)&attnb[(size_t)arr[1] * 4096 + lb_ + ac4[1] * 4];      \
    pa2 = *(const float4*)&attnb[(size_t)arr[2] * 4096 + lb_ + ac4[2] * 4];      \
  } while (0)

#define COMMIT(BUF) do {                                                         \
    *(float4*)&Vs[BUF][vrow +  0][vc4 * 4] = pv0;                                \
    *(float4*)&Vs[BUF][vrow + 16][vc4 * 4] = pv1;                                \
    *(float4*)&Vs[BUF][vrow + 32][vc4 * 4] = pv2;                                \
    *(float4*)&Vs[BUF][vrow + 48][vc4 * 4] = pv3;                                \
    *(float4*)&As[BUF][arow[0]][ac4[0] * 4] = sm4(pa0, mxv[0], ivv[0]);          \
    *(float4*)&As[BUF][arow[1]][ac4[1] * 4] = sm4(pa1, mxv[1], ivv[1]);          \
    *(float4*)&As[BUF][arow[2]][ac4[2] * 4] = sm4(pa2, mxv[2], ivv[2]);          \
  } while (0)

  float4 acc0 = make_float4(0.f, 0.f, 0.f, 0.f);
  float4 acc1 = make_float4(0.f, 0.f, 0.f, 0.f);
  float4 acc2 = make_float4(0.f, 0.f, 0.f, 0.f);

  ISSUE(0);
  asm volatile("s_waitcnt vmcnt(0)" ::: "memory");
  COMMIT(0);
  ISSUE(1);
  asm volatile("s_waitcnt lgkmcnt(0)" ::: "memory");
  __builtin_amdgcn_s_barrier();
  __builtin_amdgcn_sched_barrier(0);

  #pragma unroll 1
  for (int s = 0; s < 8; ++s) {
    const int rb = s & 1;
    #pragma unroll 4
    for (int l4 = 0; l4 < 16; ++l4) {
      float4 q0 = *(const float4*)&As[rb][tx * 3 + 0][l4 * 4];
      float4 q1 = *(const float4*)&As[rb][tx * 3 + 1][l4 * 4];
      float4 q2 = *(const float4*)&As[rb][tx * 3 + 2][l4 * 4];
      #pragma unroll
      for (int j = 0; j < 4; ++j) {
        float4 v = *(const float4*)&Vs[rb][l4 * 4 + j][ty * 4];
        float a0 = (j == 0) ? q0.x : (j == 1) ? q0.y : (j == 2) ? q0.z : q0.w;
        float a1 = (j == 0) ? q1.x : (j == 1) ? q1.y : (j == 2) ? q1.z : q1.w;
        float a2 = (j == 0) ? q2.x : (j == 1) ? q2.y : (j == 2) ? q2.z : q2.w;
        acc0.x = fmaf(a0, v.x, acc0.x); acc0.y = fmaf(a0, v.y, acc0.y);
        acc0.z = fmaf(a0, v.z, acc0.z); acc0.w = fmaf(a0, v.w, acc0.w);
        acc1.x = fmaf(a1, v.x, acc1.x); acc1.y = fmaf(a1, v.y, acc1.y);
        acc1.z = fmaf(a1, v.z, acc1.z); acc1.w = fmaf(a1, v.w, acc1.w);
        acc2.x = fmaf(a2, v.x, acc2.x); acc2.y = fmaf(a2, v.y, acc2.y);
        acc2.z = fmaf(a2, v.z, acc2.z); acc2.w = fmaf(a2, v.w, acc2.w);
      }
    }
    if (s + 1 < 8) {
      asm volatile("s_waitcnt vmcnt(0)" ::: "memory");
      COMMIT((s + 1) & 1);
      if (s + 2 < 8) ISSUE(s + 2);
      asm volatile("s_waitcnt lgkmcnt(0)" ::: "memory");
      __builtin_amdgcn_s_barrier();
      __builtin_amdgcn_sched_barrier(0);
    }
  }
#undef ISSUE
#undef COMMIT

  {
    float* dstbase = part + (((size_t)(ks * 8 + b)) * U_) * 512 + d0 + ty * 4;
    int i0 = tx * 3;
    if (i0 + 0 < U_) *(float4*)(dstbase + (size_t)(i0 + 0) * 512) = acc0;
    if (i0 + 1 < U_) *(float4*)(dstbase + (size_t)(i0 + 1) * 512) = acc1;
    if (i0 + 2 < U_) *(float4*)(dstbase + (size_t)(i0 + 2) * 512) = acc2;
  }
}

// ---- output: base fill (row-mean of Vp) + scatter s1 rows at topI ----
__global__ __launch_bounds__(256) void output_k(const float* __restrict__ V,
    const float* __restrict__ wvmean, const float* __restrict__ bvp,
    const int* __restrict__ topI, const float* __restrict__ s1, float* __restrict__ outp) {
  int b = blockIdx.y, tile = blockIdx.x;
  int l0 = tile * 64;
  int t = threadIdx.x, w = t >> 6, lane = t & 63;
  __shared__ int sel[64];
  if (t < 64) sel[t] = -1;
  __syncthreads();
  if (t < U_) {
    int lj = topI[b * U_ + t] - l0;
    if (lj >= 0 && lj < 64) sel[lj] = t;
  }
  __syncthreads();
  const float4* wv4 = (const float4*)wvmean;
  float4 wa = wv4[lane], wb = wv4[64 + lane];
  float bv = bvp[0];
  const float4* V4 = (const float4*)(V + (size_t)b * L_ * 512);
  float4* out4 = (float4*)(outp + (size_t)b * L_ * 512);
  const float4* s14 = (const float4*)s1;
  for (int r = w; r < 64; r += 4) {
    int l = l0 + r;
    int j = sel[r];
    float4 o1, o2;
    if (j >= 0) {
      o1 = s14[((size_t)(b * U_ + j)) * 128 + lane];
      o2 = s14[((size_t)(b * U_ + j)) * 128 + 64 + lane];
    } else {
      float4 va = V4[(size_t)l * 128 + lane];
      float4 vb = V4[(size_t)l * 128 + 64 + lane];
      float s = va.x * wa.x + va.y * wa.y + va.z * wa.z + va.w * wa.w
              + vb.x * wb.x + vb.y * wb.y + vb.z * wb.z + vb.w * wb.w;
      s = wave_sum(s);
      float base = s + bv;
      o1 = make_float4(base, base, base, base);
      o2 = o1;
    }
    out4[(size_t)l * 128 + lane] = o1;
    out4[(size_t)l * 128 + 64 + lane] = o2;
  }
}

extern "C" void kernel_launch(void* const* d_in, const int* in_sizes, int n_in,
                              void* d_out, int out_size, void* d_ws, size_t ws_size,
                              hipStream_t stream) {
  (void)in_sizes; (void)n_in; (void)out_size; (void)ws_size;
  const float* Q  = (const float*)d_in[0];
  const float* K  = (const float*)d_in[1];
  const float* V  = (const float*)d_in[2];
  const float* WQ = (const float*)d_in[3];
  const float* bQ = (const float*)d_in[4];
  const float* WK = (const float*)d_in[5];
  const float* bK = (const float*)d_in[6];
  const float* WV = (const float*)d_in[7];
  const float* bV = (const float*)d_in[8];
  const int* kidx = (const int*)d_in[9];
  float* ws = (float*)d_ws;
  float* out = (float*)d_out;

  float* wvmean = ws + OFF_WVMEAN;
  float* bvm    = ws + OFF_BV;
  float* wqt    = ws + OFF_WQT;
  float* wkt    = ws + OFF_WKT;
  float* kw     = ws + OFF_KW;
  float* cvec   = ws + OFF_CVEC;
  float* measp  = ws + OFF_MEAS;
  int*   topI   = (int*)(ws + OFF_TOPI);
  float* qw     = ws + OFF_QW;
  float* dvec   = ws + OFF_DVEC;
  float* sc     = ws + OFF_SC;
  float* partp  = ws + OFF_PART;
  float* mxb    = ws + OFF_SMMX;
  float* ivb    = ws + OFF_SMIV;
  float* s1     = ws + OFF_S1;

  prep_k<<<dim3(16, 16, 3), dim3(32, 8), 0, stream>>>(WQ, WK, wqt, wkt, WV, bV, wvmean, bvm);

  projpair_k<<<dim3(360), dim3(512), 0, stream>>>(K, kidx, WK, bK, bQ, cvec, wqt, kw);
  meas2p_k<<<dim3(64, 8), dim3(256), 0, stream>>>(Q, kw, cvec, measp);
  topk_k<<<dim3(8), dim3(256), 0, stream>>>(measp, topI);
  projpair_k<<<dim3(360), dim3(512), 0, stream>>>(Q, topI, WQ, bQ, bK, dvec, wkt, qw);
  scores2p_k<<<dim3(64, 8), dim3(256), 0, stream>>>(K, qw, dvec, sc);
  smred_k<<<dim3(360), dim3(256), 0, stream>>>(sc, mxb, ivb);
  attnv5_k<<<dim3(8, 8, 8), dim3(256), 0, stream>>>(V, sc, mxb, ivb, partp);
  s1red_k<<<dim3(360), dim3(512), 0, stream>>>(partp, WV, bV, s1);
  output_k<<<dim3(64, 8), dim3(256), 0, stream>>>(V, wvmean, bvm, topI, s1, out);
}

// Round 14
// 363.532 us; speedup vs baseline: 1.0892x; 1.0892x over previous
//
#include <hip/hip_runtime.h>
#include <math.h>

static constexpr int B_ = 8;
static constexpr int L_ = 4096;
static constexpr int D_ = 512;
static constexpr int U_ = 45;
static constexpr float SCALE_ = 0.04419417382415922f; // 1/sqrt(512)

// ---- workspace layout (offsets in floats) ----
static constexpr size_t OFF_WVMEAN = 0;                      // 512
static constexpr size_t OFF_BV     = 512;                    // 64
static constexpr size_t OFF_WQT    = 576;                    // 512*512
static constexpr size_t OFF_WKT    = OFF_WQT + 262144;       // 512*512
static constexpr size_t OFF_KBAR   = OFF_WKT + 262144;       // (unused, kept)
static constexpr size_t OFF_KW     = OFF_KBAR + 184320;      // 8*45*512
static constexpr size_t OFF_CVEC   = OFF_KW + 184320;        // 384
static constexpr size_t OFF_MEAS   = OFF_CVEC + 384;         // 8*4096
static constexpr size_t OFF_TOPI   = OFF_MEAS + 32768;       // 384 (ints)
static constexpr size_t OFF_QBAR   = OFF_TOPI + 384;         // (unused, kept)
static constexpr size_t OFF_QW     = OFF_QBAR + 184320;      // 8*45*512
static constexpr size_t OFF_DVEC   = OFF_QW + 184320;        // 384
static constexpr size_t OFF_SC     = OFF_DVEC + 384;         // 8*45*4096 (raw scores)
static constexpr size_t OFF_PART   = OFF_SC + 1474560;       // 8 slabs * 8*45*512
static constexpr size_t OFF_SMMX   = OFF_PART + 1474560;     // 360 row maxes
static constexpr size_t OFF_SMIV   = OFF_SMMX + 512;         // 360 row 1/sums
static constexpr size_t OFF_S1     = OFF_SMIV + 512;         // 8*45*512

__device__ __forceinline__ float wave_sum(float v) {
  #pragma unroll
  for (int m = 32; m; m >>= 1) v += __shfl_xor(v, m, 64);
  return v;
}
__device__ __forceinline__ float wave_max(float v) {
  #pragma unroll
  for (int m = 32; m; m >>= 1) v = fmaxf(v, __shfl_xor(v, m, 64));
  return v;
}

// ---- prep: transpose WQ,WK (z<2) + wvmean/bvmean (z==2, first 8 x-blocks) ----
__global__ __launch_bounds__(256) void prep_k(const float* __restrict__ WQ,
    const float* __restrict__ WK, float* __restrict__ wqt, float* __restrict__ wkt,
    const float* __restrict__ WV, const float* __restrict__ bV,
    float* __restrict__ wvmean, float* __restrict__ bvout) {
  const int z = blockIdx.z;
  const int t = threadIdx.x + threadIdx.y * 32;
  if (z < 2) {
    const float* src = z ? WK : WQ;
    float* dst = z ? wkt : wqt;
    __shared__ float tile[32][33];
    int tx = threadIdx.x, ty = threadIdx.y;
    int x = blockIdx.x * 32 + tx;
    int y0 = blockIdx.y * 32;
    for (int r = ty; r < 32; r += 8) tile[r][tx] = src[(size_t)(y0 + r) * 512 + x];
    __syncthreads();
    int xo = y0 + tx;
    int yo0 = blockIdx.x * 32;
    for (int r = ty; r < 32; r += 8) dst[(size_t)(yo0 + r) * 512 + xo] = tile[tx][r];
    return;
  }
  if (blockIdx.y != 0 || blockIdx.x >= 8) return;
  int w = t >> 6, lane = t & 63;
  const float4* W4 = (const float4*)WV;
  int mbase = (blockIdx.x * 4 + w) * 16;
  for (int i = 0; i < 16; ++i) {
    int m = mbase + i;
    float4 a = W4[(size_t)m * 128 + lane];
    float4 c = W4[(size_t)m * 128 + 64 + lane];
    float s = ((a.x + a.y) + (a.z + a.w)) + ((c.x + c.y) + (c.z + c.w));
    s = wave_sum(s);
    if (lane == 0) wvmean[m] = s * (1.0f / 512.0f);
  }
  if (blockIdx.x == 0 && w == 0) {
    const float4* b4 = (const float4*)bV;
    float4 a = b4[lane], c = b4[64 + lane];
    float s = ((a.x + a.y) + (a.z + a.w)) + ((c.x + c.y) + (c.z + c.w));
    s = wave_sum(s);
    if (lane == 0) bvout[0] = s * (1.0f / 512.0f);
  }
}

// ==== fused projection pair: one block per (b, j) row ====
__global__ __launch_bounds__(512) void projpair_k(const float* __restrict__ src,
    const int* __restrict__ idx, const float* __restrict__ W1, const float* __restrict__ b1,
    const float* __restrict__ avec, float* __restrict__ aux,
    const float* __restrict__ W2T, float* __restrict__ outp) {
  const int blk = blockIdx.x;           // 0..359
  const int b = blk / U_, j = blk % U_;
  const int t = threadIdx.x;
  __shared__ float rowA[512];
  __shared__ float rowB[512];
  __shared__ float red[8];

  const float* srow = idx ? (src + ((size_t)b * L_ + idx[b * U_ + j]) * 512)
                          : (src + ((size_t)(b * U_ + j)) * 512);
  rowA[t] = srow[t];
  __syncthreads();

  float a = b1[t];
  #pragma unroll 8
  for (int m = 0; m < 512; ++m) a = fmaf(rowA[m], W1[(size_t)m * 512 + t], a);

  if (aux) {
    float v = wave_sum(a * avec[t]);
    if ((t & 63) == 0) red[t >> 6] = v;
  }
  rowB[t] = a;
  __syncthreads();
  if (aux && t == 0) {
    float s2 = 0.f;
    #pragma unroll
    for (int k = 0; k < 8; ++k) s2 += red[k];
    aux[b * U_ + j] = s2;
  }

  float o = 0.f;
  #pragma unroll 8
  for (int m = 0; m < 512; ++m) o = fmaf(rowB[m], W2T[(size_t)m * 512 + t], o);
  outp[((size_t)(b * U_ + j)) * 512 + t] = o;
}

// ==== s1 = (sum_ls part[ls]) @ WV + bV, one block per (b,j) ====
__global__ __launch_bounds__(512) void s1red_k(const float* __restrict__ part,
    const float* __restrict__ WV, const float* __restrict__ bV, float* __restrict__ s1) {
  const int blk = blockIdx.x;
  const int t = threadIdx.x;
  __shared__ float rowA[512];
  const size_t base = (size_t)blk * 512 + t;
  float s = 0.f;
  #pragma unroll
  for (int ls = 0; ls < 8; ++ls) s += part[(size_t)ls * 184320 + base];
  rowA[t] = s;
  __syncthreads();
  float o = bV[t];
  #pragma unroll 8
  for (int m = 0; m < 512; ++m) o = fmaf(rowA[m], WV[(size_t)m * 512 + t], o);
  s1[(size_t)blk * 512 + t] = o;
}

// ==== register-blocked GEMM for meas: S = Q_tile[64x512] @ kw^T[512x48] ====
__global__ __launch_bounds__(256) void meas2_k(const float* __restrict__ Q,
    const float* __restrict__ kw, const float* __restrict__ cvec, float* __restrict__ meas) {
  const int b = blockIdx.y;
  const int l0 = blockIdx.x * 64;
  const int t = threadIdx.x;
  const int tx = t & 15, ty = t >> 4;
  const int rswz = (ty >> 1) & 3;

  __shared__ float Qs[64][68];
  __shared__ float Ks[48][68];

  float acc[4][3];
  #pragma unroll
  for (int i = 0; i < 4; ++i) { acc[i][0] = 0.f; acc[i][1] = 0.f; acc[i][2] = 0.f; }

  const float4* Q4  = (const float4*)(Q + ((size_t)b * L_ + l0) * 512);
  const float4* kw4 = (const float4*)(kw + (size_t)b * U_ * 512);

  float4 pq[4], pk[3];
  int lr[4], lc[4], kr[3], kc[3];
  #pragma unroll
  for (int p = 0; p < 4; ++p) { int idx = p * 256 + t; lr[p] = idx >> 4; lc[p] = idx & 15; }
  #pragma unroll
  for (int p = 0; p < 3; ++p) { int idx = p * 256 + t; kr[p] = idx >> 4; kc[p] = idx & 15; }

  #pragma unroll
  for (int p = 0; p < 4; ++p) pq[p] = Q4[(size_t)lr[p] * 128 + lc[p]];
  #pragma unroll
  for (int p = 0; p < 3; ++p)
    pk[p] = (kr[p] < U_) ? kw4[(size_t)kr[p] * 128 + kc[p]] : make_float4(0.f, 0.f, 0.f, 0.f);

  #pragma unroll
  for (int p = 0; p < 4; ++p) {
    int sw = (lr[p] >> 3) & 3;
    *(float4*)&Qs[lr[p]][(lc[p] ^ sw) * 4] = pq[p];
  }
  #pragma unroll
  for (int p = 0; p < 3; ++p) *(float4*)&Ks[kr[p]][kc[p] * 4] = pk[p];
  __syncthreads();

  for (int it = 0; it < 8; ++it) {
    if (it < 7) {
      int k0 = (it + 1) * 16;
      #pragma unroll
      for (int p = 0; p < 4; ++p) pq[p] = Q4[(size_t)lr[p] * 128 + k0 + lc[p]];
      #pragma unroll
      for (int p = 0; p < 3; ++p)
        pk[p] = (kr[p] < U_) ? kw4[(size_t)kr[p] * 128 + k0 + kc[p]] : make_float4(0.f, 0.f, 0.f, 0.f);
    }
    #pragma unroll 4
    for (int kk4 = 0; kk4 < 16; ++kk4) {
      float4 kv0 = *(const float4*)&Ks[tx * 3 + 0][kk4 * 4];
      float4 kv1 = *(const float4*)&Ks[tx * 3 + 1][kk4 * 4];
      float4 kv2 = *(const float4*)&Ks[tx * 3 + 2][kk4 * 4];
      int qc = (kk4 ^ rswz) * 4;
      #pragma unroll
      for (int i = 0; i < 4; ++i) {
        float4 qv = *(const float4*)&Qs[ty * 4 + i][qc];
        acc[i][0] = fmaf(qv.x, kv0.x, acc[i][0]); acc[i][0] = fmaf(qv.y, kv0.y, acc[i][0]);
        acc[i][0] = fmaf(qv.z, kv0.z, acc[i][0]); acc[i][0] = fmaf(qv.w, kv0.w, acc[i][0]);
        acc[i][1] = fmaf(qv.x, kv1.x, acc[i][1]); acc[i][1] = fmaf(qv.y, kv1.y, acc[i][1]);
        acc[i][1] = fmaf(qv.z, kv1.z, acc[i][1]); acc[i][1] = fmaf(qv.w, kv1.w, acc[i][1]);
        acc[i][2] = fmaf(qv.x, kv2.x, acc[i][2]); acc[i][2] = fmaf(qv.y, kv2.y, acc[i][2]);
        acc[i][2] = fmaf(qv.z, kv2.z, acc[i][2]); acc[i][2] = fmaf(qv.w, kv2.w, acc[i][2]);
      }
    }
    __syncthreads();
    if (it < 7) {
      #pragma unroll
      for (int p = 0; p < 4; ++p) {
        int sw = (lr[p] >> 3) & 3;
        *(float4*)&Qs[lr[p]][(lc[p] ^ sw) * 4] = pq[p];
      }
      #pragma unroll
      for (int p = 0; p < 3; ++p) *(float4*)&Ks[kr[p]][kc[p] * 4] = pk[p];
      __syncthreads();
    }
  }

  const bool valid = (tx < 15);
  float c0 = 0.f, c1 = 0.f, c2 = 0.f;
  if (valid) {
    c0 = cvec[b * U_ + tx * 3 + 0];
    c1 = cvec[b * U_ + tx * 3 + 1];
    c2 = cvec[b * U_ + tx * 3 + 2];
  }
  #pragma unroll
  for (int i = 0; i < 4; ++i) {
    float s0 = acc[i][0] + c0, s1 = acc[i][1] + c1, s2 = acc[i][2] + c2;
    float jmax = valid ? fmaxf(fmaxf(s0, s1), s2) : -3.4e38f;
    float jsum = valid ? (s0 + s1 + s2) : 0.f;
    #pragma unroll
    for (int m = 8; m; m >>= 1) {
      jmax = fmaxf(jmax, __shfl_xor(jmax, m, 64));
      jsum += __shfl_xor(jsum, m, 64);
    }
    if (tx == 0) meas[(size_t)b * L_ + l0 + ty * 4 + i] = jmax - jsum * (1.0f / 45.0f);
  }
}

// ==== same GEMM for scores (raw, pre-softmax) ====
__global__ __launch_bounds__(256) void scores2_k(const float* __restrict__ K,
    const float* __restrict__ qw, const float* __restrict__ dvec, float* __restrict__ sc) {
  const int b = blockIdx.y;
  const int l0 = blockIdx.x * 64;
  const int t = threadIdx.x;
  const int tx = t & 15, ty = t >> 4;
  const int rswz = (ty >> 1) & 3;

  __shared__ float Qs[64][68];
  __shared__ float Ks[48][68];

  float acc[4][3];
  #pragma unroll
  for (int i = 0; i < 4; ++i) { acc[i][0] = 0.f; acc[i][1] = 0.f; acc[i][2] = 0.f; }

  const float4* K4  = (const float4*)(K + ((size_t)b * L_ + l0) * 512);
  const float4* qw4 = (const float4*)(qw + (size_t)b * U_ * 512);

  float4 pq[4], pk[3];
  int lr[4], lc[4], kr[3], kc[3];
  #pragma unroll
  for (int p = 0; p < 4; ++p) { int idx = p * 256 + t; lr[p] = idx >> 4; lc[p] = idx & 15; }
  #pragma unroll
  for (int p = 0; p < 3; ++p) { int idx = p * 256 + t; kr[p] = idx >> 4; kc[p] = idx & 15; }

  #pragma unroll
  for (int p = 0; p < 4; ++p) pq[p] = K4[(size_t)lr[p] * 128 + lc[p]];
  #pragma unroll
  for (int p = 0; p < 3; ++p)
    pk[p] = (kr[p] < U_) ? qw4[(size_t)kr[p] * 128 + kc[p]] : make_float4(0.f, 0.f, 0.f, 0.f);

  #pragma unroll
  for (int p = 0; p < 4; ++p) {
    int sw = (lr[p] >> 3) & 3;
    *(float4*)&Qs[lr[p]][(lc[p] ^ sw) * 4] = pq[p];
  }
  #pragma unroll
  for (int p = 0; p < 3; ++p) *(float4*)&Ks[kr[p]][kc[p] * 4] = pk[p];
  __syncthreads();

  for (int it = 0; it < 8; ++it) {
    if (it < 7) {
      int k0 = (it + 1) * 16;
      #pragma unroll
      for (int p = 0; p < 4; ++p) pq[p] = K4[(size_t)lr[p] * 128 + k0 + lc[p]];
      #pragma unroll
      for (int p = 0; p < 3; ++p)
        pk[p] = (kr[p] < U_) ? qw4[(size_t)kr[p] * 128 + k0 + kc[p]] : make_float4(0.f, 0.f, 0.f, 0.f);
    }
    #pragma unroll 4
    for (int kk4 = 0; kk4 < 16; ++kk4) {
      float4 kv0 = *(const float4*)&Ks[tx * 3 + 0][kk4 * 4];
      float4 kv1 = *(const float4*)&Ks[tx * 3 + 1][kk4 * 4];
      float4 kv2 = *(const float4*)&Ks[tx * 3 + 2][kk4 * 4];
      int qc = (kk4 ^ rswz) * 4;
      #pragma unroll
      for (int i = 0; i < 4; ++i) {
        float4 qv = *(const float4*)&Qs[ty * 4 + i][qc];
        acc[i][0] = fmaf(qv.x, kv0.x, acc[i][0]); acc[i][0] = fmaf(qv.y, kv0.y, acc[i][0]);
        acc[i][0] = fmaf(qv.z, kv0.z, acc[i][0]); acc[i][0] = fmaf(qv.w, kv0.w, acc[i][0]);
        acc[i][1] = fmaf(qv.x, kv1.x, acc[i][1]); acc[i][1] = fmaf(qv.y, kv1.y, acc[i][1]);
        acc[i][1] = fmaf(qv.z, kv1.z, acc[i][1]); acc[i][1] = fmaf(qv.w, kv1.w, acc[i][1]);
        acc[i][2] = fmaf(qv.x, kv2.x, acc[i][2]); acc[i][2] = fmaf(qv.y, kv2.y, acc[i][2]);
        acc[i][2] = fmaf(qv.z, kv2.z, acc[i][2]); acc[i][2] = fmaf(qv.w, kv2.w, acc[i][2]);
      }
    }
    __syncthreads();
    if (it < 7) {
      #pragma unroll
      for (int p = 0; p < 4; ++p) {
        int sw = (lr[p] >> 3) & 3;
        *(float4*)&Qs[lr[p]][(lc[p] ^ sw) * 4] = pq[p];
      }
      #pragma unroll
      for (int p = 0; p < 3; ++p) *(float4*)&Ks[kr[p]][kc[p] * 4] = pk[p];
      __syncthreads();
    }
  }

  if (tx < 15) {
    float d0 = dvec[b * U_ + tx * 3 + 0];
    float d1 = dvec[b * U_ + tx * 3 + 1];
    float d2 = dvec[b * U_ + tx * 3 + 2];
    #pragma unroll
    for (int i = 0; i < 4; ++i) {
      int l = l0 + ty * 4 + i;
      sc[((size_t)(b * U_ + tx * 3 + 0)) * 4096 + l] = (acc[i][0] + d0) * SCALE_;
      sc[((size_t)(b * U_ + tx * 3 + 1)) * 4096 + l] = (acc[i][1] + d1) * SCALE_;
      sc[((size_t)(b * U_ + tx * 3 + 2)) * 4096 + l] = (acc[i][2] + d2) * SCALE_;
    }
  }
}

// ---- top-45 indices per batch (iterative argmax; ties -> lower index) ----
__global__ __launch_bounds__(256) void topk_k(const float* __restrict__ meas, int* __restrict__ topI) {
  int b = blockIdx.x, t = threadIdx.x;
  __shared__ unsigned long long keys[4096];
  __shared__ unsigned long long wred[4];
  for (int i = t; i < 4096; i += 256) {
    float m = meas[(size_t)b * 4096 + i];
    unsigned u = __float_as_uint(m);
    u = (u & 0x80000000u) ? ~u : (u | 0x80000000u);
    keys[i] = ((unsigned long long)u << 32) | (unsigned)(4095 - i);
  }
  __syncthreads();
  for (int it = 0; it < U_; ++it) {
    unsigned long long lm = 0ull;
    for (int i = t; i < 4096; i += 256) { unsigned long long k = keys[i]; lm = k > lm ? k : lm; }
    #pragma unroll
    for (int m = 32; m; m >>= 1) { unsigned long long o = __shfl_xor(lm, m, 64); lm = o > lm ? o : lm; }
    if ((t & 63) == 0) wred[t >> 6] = lm;
    __syncthreads();
    if (t == 0) {
      unsigned long long f = wred[0];
      for (int k2 = 1; k2 < 4; ++k2) f = wred[k2] > f ? wred[k2] : f;
      int idxl = 4095 - (int)(f & 0xFFFFFFFFull);
      topI[b * U_ + it] = idxl;
      keys[idxl] = 0ull;
    }
    __syncthreads();
  }
}

// ---- softmax reduce only: mx[row], inv[row] = 1/sum(exp(x-mx)) ----
__global__ __launch_bounds__(256) void smred_k(const float* __restrict__ sc,
    float* __restrict__ mxb, float* __restrict__ ivb) {
  int row = blockIdx.x;
  int t = threadIdx.x;
  const float4* s4 = (const float4*)(sc + (size_t)row * 4096);
  __shared__ float red[4];
  float4 v[4];
  #pragma unroll
  for (int p = 0; p < 4; ++p) v[p] = s4[t + p * 256];
  float lmax = -3.4e38f;
  #pragma unroll
  for (int p = 0; p < 4; ++p)
    lmax = fmaxf(lmax, fmaxf(fmaxf(v[p].x, v[p].y), fmaxf(v[p].z, v[p].w)));
  lmax = wave_max(lmax);
  if ((t & 63) == 0) red[t >> 6] = lmax;
  __syncthreads();
  float mx = fmaxf(fmaxf(red[0], red[1]), fmaxf(red[2], red[3]));
  __syncthreads();
  float lsum = 0.f;
  #pragma unroll
  for (int p = 0; p < 4; ++p)
    lsum += expf(v[p].x - mx) + expf(v[p].y - mx) + expf(v[p].z - mx) + expf(v[p].w - mx);
  lsum = wave_sum(lsum);
  if ((t & 63) == 0) red[t >> 6] = lsum;
  __syncthreads();
  if (t == 0) {
    mxb[row] = mx;
    ivb[row] = 1.0f / (red[0] + red[1] + red[2] + red[3]);
  }
}

__device__ __forceinline__ float4 sm4(float4 v, float m, float iv) {
  return make_float4(expf(v.x - m) * iv, expf(v.y - m) * iv,
                     expf(v.z - m) * iv, expf(v.w - m) * iv);
}

// ==== attnV v5 + inline softmax ====
__global__ __launch_bounds__(256) void attnv5_k(const float* __restrict__ V,
    const float* __restrict__ attn, const float* __restrict__ mxb,
    const float* __restrict__ ivb, float* __restrict__ part) {
  const int b = blockIdx.x, ks = blockIdx.y, dh = blockIdx.z;
  const int d0 = dh * 64;
  const int t = threadIdx.x;
  const int tx = t & 15, ty = t >> 4;

  __shared__ float As[2][48][68];
  __shared__ float Vs[2][64][68];

  const float* attnb = attn + (size_t)b * U_ * 4096 + (size_t)ks * 512;
  const float* Vb = V + ((size_t)b * L_ + (size_t)ks * 512) * 512 + d0;

  const int vrow = t >> 4, vc4 = t & 15;
  int arow[3], ac4[3], arr[3];
  float mxv[3], ivv[3];
  #pragma unroll
  for (int p = 0; p < 3; ++p) {
    int idx = p * 256 + t;
    arow[p] = idx >> 4; ac4[p] = idx & 15;
    arr[p] = arow[p] < U_ ? arow[p] : U_ - 1;
    mxv[p] = mxb[b * U_ + arr[p]];
    ivv[p] = ivb[b * U_ + arr[p]];
  }

  float4 pv0, pv1, pv2, pv3, pa0, pa1, pa2;

#define ISSUE(S) do { const int lb_ = (S) * 64;                                  \
    pv0 = *(const float4*)&Vb[(size_t)(lb_ + vrow +  0) * 512 + vc4 * 4];        \
    pv1 = *(const float4*)&Vb[(size_t)(lb_ + vrow + 16) * 512 + vc4 * 4];        \
    pv2 = *(const float4*)&Vb[(size_t)(lb_ + vrow + 32) * 512 + vc4 * 4];        \
    pv3 = *(const float4*)&Vb[(size_t)(lb_ + vrow + 48) * 512 + vc4 * 4];        \
    pa0 = *(const float4*)&attnb[(size_t)arr[0] * 4096 + lb_ + ac4[0] * 4];      \
    pa1 = *(const float4*)&attnb[(size_t)arr[1] * 4096 + lb_ + ac4[1] * 4];      \
    pa2 = *(const float4*)&attnb[(size_t)arr[2] * 4096 + lb_ + ac4[2] * 4];      \
  } while (0)

#define COMMIT(BUF) do {                                                         \
    *(float4*)&Vs[BUF][vrow +  0][vc4 * 4] = pv0;                                \
    *(float4*)&Vs[BUF][vrow + 16][vc4 * 4] = pv1;                                \
    *(float4*)&Vs[BUF][vrow + 32][vc4 * 4] = pv2;                                \
    *(float4*)&Vs[BUF][vrow + 48][vc4 * 4] = pv3;                                \
    *(float4*)&As[BUF][arow[0]][ac4[0] * 4] = sm4(pa0, mxv[0], ivv[0]);          \
    *(float4*)&As[BUF][arow[1]][ac4[1] * 4] = sm4(pa1, mxv[1], ivv[1]);          \
    *(float4*)&As[BUF][arow[2]][ac4[2] * 4] = sm4(pa2, mxv[2], ivv[2]);          \
  } while (0)

  float4 acc0 = make_float4(0.f, 0.f, 0.f, 0.f);
  float4 acc1 = make_float4(0.f, 0.f, 0.f, 0.f);
  float4 acc2 = make_float4(0.f, 0.f, 0.f, 0.f);

  ISSUE(0);
  asm volatile("s_waitcnt vmcnt(0)" ::: "memory");
  COMMIT(0);
  ISSUE(1);
  asm volatile("s_waitcnt lgkmcnt(0)" ::: "memory");
  __builtin_amdgcn_s_barrier();
  __builtin_amdgcn_sched_barrier(0);

  #pragma unroll 1
  for (int s = 0; s < 8; ++s) {
    const int rb = s & 1;
    #pragma unroll 4
    for (int l4 = 0; l4 < 16; ++l4) {
      float4 q0 = *(const float4*)&As[rb][tx * 3 + 0][l4 * 4];
      float4 q1 = *(const float4*)&As[rb][tx * 3 + 1][l4 * 4];
      float4 q2 = *(const float4*)&As[rb][tx * 3 + 2][l4 * 4];
      #pragma unroll
      for (int j = 0; j < 4; ++j) {
        float4 v = *(const float4*)&Vs[rb][l4 * 4 + j][ty * 4];
        float a0 = (j == 0) ? q0.x : (j == 1) ? q0.y : (j == 2) ? q0.z : q0.w;
        float a1 = (j == 0) ? q1.x : (j == 1) ? q1.y : (j == 2) ? q1.z : q1.w;
        float a2 = (j == 0) ? q2.x : (j == 1) ? q2.y : (j == 2) ? q2.z : q2.w;
        acc0.x = fmaf(a0, v.x, acc0.x); acc0.y = fmaf(a0, v.y, acc0.y);
        acc0.z = fmaf(a0, v.z, acc0.z); acc0.w = fmaf(a0, v.w, acc0.w);
        acc1.x = fmaf(a1, v.x, acc1.x); acc1.y = fmaf(a1, v.y, acc1.y);
        acc1.z = fmaf(a1, v.z, acc1.z); acc1.w = fmaf(a1, v.w, acc1.w);
        acc2.x = fmaf(a2, v.x, acc2.x); acc2.y = fmaf(a2, v.y, acc2.y);
        acc2.z = fmaf(a2, v.z, acc2.z); acc2.w = fmaf(a2, v.w, acc2.w);
      }
    }
    if (s + 1 < 8) {
      asm volatile("s_waitcnt vmcnt(0)" ::: "memory");
      COMMIT((s + 1) & 1);
      if (s + 2 < 8) ISSUE(s + 2);
      asm volatile("s_waitcnt lgkmcnt(0)" ::: "memory");
      __builtin_amdgcn_s_barrier();
      __builtin_amdgcn_sched_barrier(0);
    }
  }
#undef ISSUE
#undef COMMIT

  {
    float* dstbase = part + (((size_t)(ks * 8 + b)) * U_) * 512 + d0 + ty * 4;
    int i0 = tx * 3;
    if (i0 + 0 < U_) *(float4*)(dstbase + (size_t)(i0 + 0) * 512) = acc0;
    if (i0 + 1 < U_) *(float4*)(dstbase + (size_t)(i0 + 1) * 512) = acc1;
    if (i0 + 2 < U_) *(float4*)(dstbase + (size_t)(i0 + 2) * 512) = acc2;
  }
}

// ---- output: base fill (row-mean of Vp) + scatter s1 rows at topI ----
__global__ __launch_bounds__(256) void output_k(const float* __restrict__ V,
    const float* __restrict__ wvmean, const float* __restrict__ bvp,
    const int* __restrict__ topI, const float* __restrict__ s1, float* __restrict__ outp) {
  int b = blockIdx.y, tile = blockIdx.x;
  int l0 = tile * 64;
  int t = threadIdx.x, w = t >> 6, lane = t & 63;
  __shared__ int sel[64];
  if (t < 64) sel[t] = -1;
  __syncthreads();
  if (t < U_) {
    int lj = topI[b * U_ + t] - l0;
    if (lj >= 0 && lj < 64) sel[lj] = t;
  }
  __syncthreads();
  const float4* wv4 = (const float4*)wvmean;
  float4 wa = wv4[lane], wb = wv4[64 + lane];
  float bv = bvp[0];
  const float4* V4 = (const float4*)(V + (size_t)b * L_ * 512);
  float4* out4 = (float4*)(outp + (size_t)b * L_ * 512);
  const float4* s14 = (const float4*)s1;
  for (int r = w; r < 64; r += 4) {
    int l = l0 + r;
    int j = sel[r];
    float4 o1, o2;
    if (j >= 0) {
      o1 = s14[((size_t)(b * U_ + j)) * 128 + lane];
      o2 = s14[((size_t)(b * U_ + j)) * 128 + 64 + lane];
    } else {
      float4 va = V4[(size_t)l * 128 + lane];
      float4 vb = V4[(size_t)l * 128 + 64 + lane];
      float s = va.x * wa.x + va.y * wa.y + va.z * wa.z + va.w * wa.w
              + vb.x * wb.x + vb.y * wb.y + vb.z * wb.z + vb.w * wb.w;
      s = wave_sum(s);
      float base = s + bv;
      o1 = make_float4(base, base, base, base);
      o2 = o1;
    }
    out4[(size_t)l * 128 + lane] = o1;
    out4[(size_t)l * 128 + 64 + lane] = o2;
  }
}

extern "C" void kernel_launch(void* const* d_in, const int* in_sizes, int n_in,
                              void* d_out, int out_size, void* d_ws, size_t ws_size,
                              hipStream_t stream) {
  (void)in_sizes; (void)n_in; (void)out_size; (void)ws_size;
  const float* Q  = (const float*)d_in[0];
  const float* K  = (const float*)d_in[1];
  const float* V  = (const float*)d_in[2];
  const float* WQ = (const float*)d_in[3];
  const float* bQ = (const float*)d_in[4];
  const float* WK = (const float*)d_in[5];
  const float* bK = (const float*)d_in[6];
  const float* WV = (const float*)d_in[7];
  const float* bV = (const float*)d_in[8];
  const int* kidx = (const int*)d_in[9];
  float* ws = (float*)d_ws;
  float* out = (float*)d_out;

  float* wvmean = ws + OFF_WVMEAN;
  float* bvm    = ws + OFF_BV;
  float* wqt    = ws + OFF_WQT;
  float* wkt    = ws + OFF_WKT;
  float* kw     = ws + OFF_KW;
  float* cvec   = ws + OFF_CVEC;
  float* measp  = ws + OFF_MEAS;
  int*   topI   = (int*)(ws + OFF_TOPI);
  float* qw     = ws + OFF_QW;
  float* dvec   = ws + OFF_DVEC;
  float* sc     = ws + OFF_SC;
  float* partp  = ws + OFF_PART;
  float* mxb    = ws + OFF_SMMX;
  float* ivb    = ws + OFF_SMIV;
  float* s1     = ws + OFF_S1;

  prep_k<<<dim3(16, 16, 3), dim3(32, 8), 0, stream>>>(WQ, WK, wqt, wkt, WV, bV, wvmean, bvm);

  projpair_k<<<dim3(360), dim3(512), 0, stream>>>(K, kidx, WK, bK, bQ, cvec, wqt, kw);
  meas2_k<<<dim3(64, 8), dim3(256), 0, stream>>>(Q, kw, cvec, measp);
  topk_k<<<dim3(8), dim3(256), 0, stream>>>(measp, topI);
  projpair_k<<<dim3(360), dim3(512), 0, stream>>>(Q, topI, WQ, bQ, bK, dvec, wkt, qw);
  scores2_k<<<dim3(64, 8), dim3(256), 0, stream>>>(K, qw, dvec, sc);
  smred_k<<<dim3(360), dim3(256), 0, stream>>>(sc, mxb, ivb);
  attnv5_k<<<dim3(8, 8, 8), dim3(256), 0, stream>>>(V, sc, mxb, ivb, partp);
  s1red_k<<<dim3(360), dim3(512), 0, stream>>>(partp, WV, bV, s1);
  output_k<<<dim3(64, 8), dim3(256), 0, stream>>>(V, wvmean, bvm, topI, s1, out);
}